// Round 3
// baseline (399.153 us; speedup 1.0000x reference)
//
#include <hip/hip_runtime.h>
#include <hip/hip_bf16.h>
#include <stdint.h>

// Problem constants (B=2, S=2048, D=1024, H=16, hd=64)
#define DIMD 1024
#define SEQ  2048
#define NH   16
#define MROWS 4096   // B*S
#define NQ   65536   // total q rows across (b,h) = 32*2048

typedef __bf16 bf16_t;
typedef bf16_t bf16x8 __attribute__((ext_vector_type(8)));
typedef float  f32x4  __attribute__((ext_vector_type(4)));
typedef unsigned short u16;
typedef unsigned short u16x4 __attribute__((ext_vector_type(4)));
typedef unsigned short u16x8 __attribute__((ext_vector_type(8)));
typedef unsigned int   u32;
typedef u32 u32x2 __attribute__((ext_vector_type(2)));

static __device__ __forceinline__ f32x4 mfma16(bf16x8 a, bf16x8 b, f32x4 c) {
    return __builtin_amdgcn_mfma_f32_16x16x32_bf16(a, b, c, 0, 0, 0);
}

static __device__ __forceinline__ float fast_exp2(float x) {
#if __has_builtin(__builtin_amdgcn_exp2f)
    return __builtin_amdgcn_exp2f(x);
#else
    return exp2f(x);
#endif
}

// Split fp32 into hi/lo bf16 by truncation: x ~= hi + lo, rel err <= 2^-16
static __device__ __forceinline__ void split_bf16(float x, u16& h, u16& l) {
    u32 u = __float_as_uint(x);
    u16 hu = (u16)(u >> 16);
    float xh = __uint_as_float((u32)hu << 16);
    float lo = x - xh;
    h = hu;
    l = (u16)(__float_as_uint(lo) >> 16);
}

// pack two fp32 -> dword of 2 bf16 (truncate)
static __device__ __forceinline__ u32 pack_bf16(float a, float b) {
    return (__float_as_uint(a) >> 16) | (__float_as_uint(b) & 0xffff0000u);
}
// round-to-nearest-ish (half-up) variant for output partials
static __device__ __forceinline__ u32 pack_bf16_rn(float a, float b) {
    u32 ua = __float_as_uint(a) + 0x8000u;
    u32 ub = __float_as_uint(b) + 0x8000u;
    return (ua >> 16) | (ub & 0xffff0000u);
}
static __device__ __forceinline__ float bf_to_f(u16 v) {
    return __uint_as_float((u32)v << 16);
}

// ---------------------------------------------------------------------------
// Kernel 1: W[1024][1024] f32 -> W^T split into hi/lo bf16, 3 weights (z).
// WTH/WTL layout: [z][n][k] = split(W[k][n])
// ---------------------------------------------------------------------------
__global__ __launch_bounds__(256) void transW_split(
    const float* __restrict__ w0, const float* __restrict__ w1, const float* __restrict__ w2,
    u16* __restrict__ WTH, u16* __restrict__ WTL) {
    const int z = blockIdx.z;
    const float* W = z == 0 ? w0 : z == 1 ? w1 : w2;
    __shared__ float tile[32][33];
    int tx = threadIdx.x & 31, ty = threadIdx.x >> 5;   // 32 x 8
    int x0 = blockIdx.x * 32, y0 = blockIdx.y * 32;
    #pragma unroll
    for (int i = 0; i < 32; i += 8)
        tile[ty + i][tx] = W[(size_t)(y0 + ty + i) * DIMD + x0 + tx];
    __syncthreads();
    #pragma unroll
    for (int i = 0; i < 32; i += 8) {
        float v = tile[tx][ty + i];            // = W[y0+tx][x0+ty+i]
        u16 hh, ll; split_bf16(v, hh, ll);
        size_t o = (size_t)z * (DIMD * DIMD) + (size_t)(x0 + ty + i) * DIMD + (y0 + tx);
        WTH[o] = hh; WTL[o] = ll;
    }
}

// ---------------------------------------------------------------------------
// Kernel 2: 3 projection GEMMs in one launch (z selects q/k/v).
//   P = X @ W via split-bf16 (3 MFMA per tile pair).
//   A (X fp32): split in-kernel during staging. B (W^T): pre-split bf16,
//   staged with pure vector copies. z==0 folds in scale*log2(e).
// Block 256 thr (4 waves 2x2), tile 128x128, BK=32. LDS 40KB.
// ---------------------------------------------------------------------------
__global__ __launch_bounds__(256, 3) void proj_gemm3(
    const float* __restrict__ xq, const float* __restrict__ xk, const float* __restrict__ xv,
    const u16* __restrict__ WTH, const u16* __restrict__ WTL,
    u16* __restrict__ qh, u16* __restrict__ ql,
    u16* __restrict__ kh, u16* __restrict__ kl,
    u16* __restrict__ vh) {

    const int z = blockIdx.z;
    const float* X = z == 0 ? xq : z == 1 ? xk : xv;
    const u16* BH = WTH + (size_t)z * (DIMD * DIMD);
    const u16* BL = WTL + (size_t)z * (DIMD * DIMD);
    u16* outH = z == 0 ? qh : z == 1 ? kh : vh;
    u16* outL = z == 0 ? ql : kl;               // unused when z==2 (guarded)
    const float oscale = z == 0 ? 0.0450842200278f : 1.0f;  // (1/32)*log2(e)

    // stride 40 u16 (80B): 16B-aligned rows, uniform bank spread
    __shared__ u16 AsH[128][40], AsL[128][40], BsH[128][40], BsL[128][40];

    const int tid  = threadIdx.x;
    const int lane = tid & 63, wave = tid >> 6;
    const int quad = lane >> 4, l16 = lane & 15;
    const int wy = wave >> 1, wx = wave & 1;
    const int m0 = blockIdx.y * 128, n0 = blockIdx.x * 128;

    f32x4 acc[4][4];
    #pragma unroll
    for (int mt = 0; mt < 4; mt++)
        #pragma unroll
        for (int nt = 0; nt < 4; nt++) acc[mt][nt] = (f32x4)0.0f;

    for (int k0 = 0; k0 < DIMD; k0 += 32) {
        // A: 128x32 f32 -> split hi/lo (1024 f32x4 chunks, 4/thread)
        #pragma unroll
        for (int i = 0; i < 4; i++) {
            int f = i * 256 + tid;
            int r = f >> 3, c = (f & 7) * 4;
            f32x4 a = *(const f32x4*)&X[(size_t)(m0 + r) * DIMD + k0 + c];
            u16x4 ah, al;
            #pragma unroll
            for (int j = 0; j < 4; j++) {
                u16 hh, ll; split_bf16(a[j], hh, ll);
                ah[j] = hh; al[j] = ll;
            }
            *(u16x4*)&AsH[r][c] = ah;
            *(u16x4*)&AsL[r][c] = al;
        }
        // B: 128x32 u16 x2 arrays (512 16B-chunks each, 2/thread/array)
        #pragma unroll
        for (int i = 0; i < 2; i++) {
            int f = i * 256 + tid;
            int r = f >> 2, c = (f & 3) * 8;
            *(u16x8*)&BsH[r][c] = *(const u16x8*)&BH[(size_t)(n0 + r) * DIMD + k0 + c];
            *(u16x8*)&BsL[r][c] = *(const u16x8*)&BL[(size_t)(n0 + r) * DIMD + k0 + c];
        }
        __syncthreads();

        bf16x8 aH[4], aL[4], bH[4], bL[4];
        #pragma unroll
        for (int mt = 0; mt < 4; mt++) {
            int r = wy * 64 + mt * 16 + l16;
            aH[mt] = *(const bf16x8*)&AsH[r][quad * 8];
            aL[mt] = *(const bf16x8*)&AsL[r][quad * 8];
        }
        #pragma unroll
        for (int nt = 0; nt < 4; nt++) {
            int r = wx * 64 + nt * 16 + l16;
            bH[nt] = *(const bf16x8*)&BsH[r][quad * 8];
            bL[nt] = *(const bf16x8*)&BsL[r][quad * 8];
        }
        #pragma unroll
        for (int mt = 0; mt < 4; mt++)
            #pragma unroll
            for (int nt = 0; nt < 4; nt++) {
                acc[mt][nt] = mfma16(aH[mt], bH[nt], acc[mt][nt]);
                acc[mt][nt] = mfma16(aH[mt], bL[nt], acc[mt][nt]);
                acc[mt][nt] = mfma16(aL[mt], bH[nt], acc[mt][nt]);
            }
        __syncthreads();
    }

    #pragma unroll
    for (int mt = 0; mt < 4; mt++)
        #pragma unroll
        for (int nt = 0; nt < 4; nt++)
            #pragma unroll
            for (int r = 0; r < 4; r++) {
                int row = m0 + wy * 64 + mt * 16 + quad * 4 + r;
                int col = n0 + wx * 64 + nt * 16 + l16;
                u16 hh, ll; split_bf16(acc[mt][nt][r] * oscale, hh, ll);
                outH[(size_t)row * DIMD + col] = hh;
                if (z != 2) outL[(size_t)row * DIMD + col] = ll;
            }
}

// ---------------------------------------------------------------------------
// Kernel 3: per-head V transpose: vh slab [bh][2048][64] -> vt [bh][64][2048]
// ---------------------------------------------------------------------------
__global__ __launch_bounds__(256) void transposeV(
    const u16* __restrict__ vh, u16* __restrict__ vt) {
    __shared__ u16 Ls[64][72];
    const int tid = threadIdx.x;
    const int bh = blockIdx.y;
    const int s0 = blockIdx.x * 64;
    const size_t slab = (size_t)bh * (SEQ * 64);
    #pragma unroll
    for (int i = 0; i < 2; i++) {
        int f = i * 256 + tid;
        int r = f >> 3, c = (f & 7) * 8;
        *(u16x8*)&Ls[r][c] = *(const u16x8*)(vh + slab + (size_t)(s0 + r) * 64 + c);
    }
    __syncthreads();
    #pragma unroll
    for (int i = 0; i < 2; i++) {
        int f = i * 256 + tid;
        int d = f >> 3, j = (f & 7) * 8;
        u16x8 o;
        #pragma unroll
        for (int jj = 0; jj < 8; jj++) o[jj] = Ls[j + jj][d];
        *(u16x8*)(vt + slab + (size_t)d * SEQ + s0 + j) = o;
    }
}

// ---------------------------------------------------------------------------
// Kernel 4: flash attention, S^T formulation, no __syncthreads in main loop.
//   S^T = K·Q^T (swapped MFMA operands): each lane's C column = one q, so
//   softmax stats are per-lane scalars, reductions are 2 shuffles.
//   K hi/lo and V^T fragments are loaded straight from global (L2); only the
//   P (C->A layout) round-trip uses LDS, and it is wave-local.
//   Block = 2 waves, each wave 32 q rows (m=2). KV split in 2 halves ->
//   grid (32 qtile, 32 bh, 2 split) = 2048 blocks = 8/CU at VGPR<=128.
//   Partials (un-normalized O in bf16-rn, M, L) written per split half.
// ---------------------------------------------------------------------------
__global__ __launch_bounds__(128, 4) void flash2(
    const u16* __restrict__ qh, const u16* __restrict__ ql,
    const u16* __restrict__ kh, const u16* __restrict__ kl,
    const u16* __restrict__ vt,
    u16* __restrict__ Opart, float* __restrict__ Mpart, float* __restrict__ Lpart) {

    __shared__ u16 Ps[2][32][72];   // per-wave P tile [32 q][64 kv], stride 72

    const int tid  = threadIdx.x;
    const int lane = tid & 63, wave = tid >> 6;
    const int quad = lane >> 4, l16 = lane & 15;
    const int bh = blockIdx.y;
    const int z  = blockIdx.z;
    const size_t slab = (size_t)bh * (SEQ * 64);
    const int q0 = blockIdx.x * 64 + wave * 32;     // this wave's q base

    // Q fragments (B-operand layout == A-layout): rows q0+mq*16+l16
    bf16x8 qfH[2][2], qfL[2][2];
    #pragma unroll
    for (int mq = 0; mq < 2; mq++) {
        const size_t rb = slab + (size_t)(q0 + mq * 16 + l16) * 64;
        #pragma unroll
        for (int kk = 0; kk < 2; kk++) {
            qfH[mq][kk] = *(const bf16x8*)(qh + rb + kk * 32 + quad * 8);
            qfL[mq][kk] = *(const bf16x8*)(ql + rb + kk * 32 + quad * 8);
        }
    }

    f32x4 O[2][4];
    float M[2] = {-3.0e38f, -3.0e38f}, L[2] = {0.0f, 0.0f};
    #pragma unroll
    for (int mq = 0; mq < 2; mq++)
        #pragma unroll
        for (int nv = 0; nv < 4; nv++) O[mq][nv] = (f32x4)0.0f;

    for (int t = 0; t < 16; t++) {
        const int j0 = z * 1024 + t * 64;

        // S^T = K·Q^T (split: Kh·Qh + Kl·Qh + Kh·Ql); K frags from global
        f32x4 St[2][4];
        #pragma unroll
        for (int mq = 0; mq < 2; mq++)
            #pragma unroll
            for (int nt = 0; nt < 4; nt++) St[mq][nt] = (f32x4)0.0f;
        #pragma unroll
        for (int nt = 0; nt < 4; nt++) {
            const size_t rb = slab + (size_t)(j0 + nt * 16 + l16) * 64;
            #pragma unroll
            for (int kk = 0; kk < 2; kk++) {
                bf16x8 kH = *(const bf16x8*)(kh + rb + kk * 32 + quad * 8);
                bf16x8 kL = *(const bf16x8*)(kl + rb + kk * 32 + quad * 8);
                #pragma unroll
                for (int mq = 0; mq < 2; mq++) {
                    St[mq][nt] = mfma16(kH, qfH[mq][kk], St[mq][nt]);
                    St[mq][nt] = mfma16(kL, qfH[mq][kk], St[mq][nt]);
                    St[mq][nt] = mfma16(kH, qfL[mq][kk], St[mq][nt]);
                }
            }
        }

        // online softmax (per-lane scalar state; 2 shuffles per reduction)
        #pragma unroll
        for (int mq = 0; mq < 2; mq++) {
            float mx = St[mq][0][0];
            #pragma unroll
            for (int nt = 0; nt < 4; nt++)
                #pragma unroll
                for (int r = 0; r < 4; r++) mx = fmaxf(mx, St[mq][nt][r]);
            mx = fmaxf(mx, __shfl_xor(mx, 16));
            mx = fmaxf(mx, __shfl_xor(mx, 32));
            float Mn = fmaxf(M[mq], mx);
            float al = fast_exp2(M[mq] - Mn);
            M[mq] = Mn;
            float rs = 0.0f;
            #pragma unroll
            for (int nt = 0; nt < 4; nt++)
                #pragma unroll
                for (int r = 0; r < 4; r++) {
                    float p = fast_exp2(St[mq][nt][r] - Mn);
                    St[mq][nt][r] = p;
                    rs += p;
                }
            rs += __shfl_xor(rs, 16);
            rs += __shfl_xor(rs, 32);
            L[mq] = L[mq] * al + rs;
            #pragma unroll
            for (int nv = 0; nv < 4; nv++) O[mq][nv] *= al;
            // P store: pack 4 kv-consecutive bf16 -> one b64 per nt
            #pragma unroll
            for (int nt = 0; nt < 4; nt++) {
                u32x2 d;
                d[0] = pack_bf16(St[mq][nt][0], St[mq][nt][1]);
                d[1] = pack_bf16(St[mq][nt][2], St[mq][nt][3]);
                *(u32x2*)&Ps[wave][mq * 16 + l16][nt * 16 + quad * 4] = d;
            }
        }

        // O^T += V^T · P^T  (V^T frags from global, P from wave-local LDS)
        #pragma unroll
        for (int kk = 0; kk < 2; kk++) {
            bf16x8 pB[2];
            #pragma unroll
            for (int mq = 0; mq < 2; mq++)
                pB[mq] = *(const bf16x8*)&Ps[wave][mq * 16 + l16][kk * 32 + quad * 8];
            #pragma unroll
            for (int nv = 0; nv < 4; nv++) {
                bf16x8 vF = *(const bf16x8*)(vt + slab + (size_t)(nv * 16 + l16) * SEQ
                                             + j0 + kk * 32 + quad * 8);
                #pragma unroll
                for (int mq = 0; mq < 2; mq++)
                    O[mq][nv] = mfma16(vF, pB[mq], O[mq][nv]);
            }
        }
    }

    // epilogue: store un-normalized O (bf16-rn), M, L per split half
    const int qgb = bh * SEQ + q0;
    #pragma unroll
    for (int mq = 0; mq < 2; mq++) {
        const int qg = qgb + mq * 16 + l16;
        #pragma unroll
        for (int nv = 0; nv < 4; nv++) {
            u32x2 d;
            d[0] = pack_bf16_rn(O[mq][nv][0], O[mq][nv][1]);
            d[1] = pack_bf16_rn(O[mq][nv][2], O[mq][nv][3]);
            *(u32x2*)(Opart + ((size_t)(z * NQ + qg)) * 64 + nv * 16 + quad * 4) = d;
        }
        if (quad == 0) {
            Mpart[z * NQ + qg] = M[mq];
            Lpart[z * NQ + qg] = L[mq];
        }
    }
}

// ---------------------------------------------------------------------------
// Kernel 5: combine the 2 KV-split halves -> final out [B,S,D]
// ---------------------------------------------------------------------------
__global__ __launch_bounds__(256) void combine2(
    const u16* __restrict__ Opart, const float* __restrict__ Mpart,
    const float* __restrict__ Lpart, float* __restrict__ out) {
    int idx = blockIdx.x * 256 + threadIdx.x;       // 0 .. NQ*16-1
    int qg = idx >> 4, c4 = (idx & 15) * 4;
    float M0 = Mpart[qg], M1 = Mpart[NQ + qg];
    float L0 = Lpart[qg], L1 = Lpart[NQ + qg];
    float Ms = fmaxf(M0, M1);
    float w0 = fast_exp2(M0 - Ms), w1 = fast_exp2(M1 - Ms);
    float inv = 1.0f / (w0 * L0 + w1 * L1);
    u16x4 a = *(const u16x4*)&Opart[(size_t)qg * 64 + c4];
    u16x4 b = *(const u16x4*)&Opart[((size_t)NQ + qg) * 64 + c4];
    f32x4 o;
    #pragma unroll
    for (int j = 0; j < 4; j++)
        o[j] = (w0 * bf_to_f(a[j]) + w1 * bf_to_f(b[j])) * inv;
    int bh = qg >> 11, s = qg & 2047;
    int bb = bh >> 4, h = bh & 15;
    *(f32x4*)&out[((size_t)(bb * SEQ + s)) * DIMD + h * 64 + c4] = o;
}

// ---------------------------------------------------------------------------
extern "C" void kernel_launch(void* const* d_in, const int* in_sizes, int n_in,
                              void* d_out, int out_size, void* d_ws, size_t ws_size,
                              hipStream_t stream) {
    const float* q  = (const float*)d_in[0];
    const float* k  = (const float*)d_in[1];
    const float* v  = (const float*)d_in[2];
    const float* wq = (const float*)d_in[3];
    const float* wk = (const float*)d_in[4];
    const float* wv = (const float*)d_in[5];
    float* out = (float*)d_out;

    char* ws = (char*)d_ws;
    const size_t MB = 1 << 20;
    // Region A (0..17MB): WT hi/lo (12MB) early; Opart(16MB)+M/L(1MB) later.
    u16*   WTH   = (u16*)(ws + 0);
    u16*   WTL   = (u16*)(ws + 6 * MB);
    u16*   Opart = (u16*)(ws + 0);                  // overlays WT (dead by then)
    float* Mpart = (float*)(ws + 16 * MB);
    float* Lpart = (float*)(ws + 16 * MB + 512 * 1024);
    // Region B (17MB..65MB): projection outputs + V^T
    u16* qh = (u16*)(ws + 17 * MB);
    u16* ql = (u16*)(ws + 25 * MB);
    u16* kh = (u16*)(ws + 33 * MB);
    u16* kl = (u16*)(ws + 41 * MB);
    u16* vh = (u16*)(ws + 49 * MB);
    u16* vt = (u16*)(ws + 57 * MB);

    transW_split<<<dim3(32, 32, 3), 256, 0, stream>>>(wq, wk, wv, WTH, WTL);

    proj_gemm3<<<dim3(DIMD / 128, MROWS / 128, 3), 256, 0, stream>>>(
        q, k, v, WTH, WTL, qh, ql, kh, kl, vh);

    transposeV<<<dim3(SEQ / 64, 2 * NH), 256, 0, stream>>>(vh, vt);

    flash2<<<dim3(SEQ / 64, 2 * NH, 2), 128, 0, stream>>>(
        qh, ql, kh, kl, vt, Opart, Mpart, Lpart);

    combine2<<<dim3(NQ * 16 / 256), 256, 0, stream>>>(Opart, Mpart, Lpart, out);
}

// Round 4
// 269.472 us; speedup vs baseline: 1.4812x; 1.4812x over previous
//
#include <hip/hip_runtime.h>
#include <hip/hip_bf16.h>
#include <stdint.h>

// Problem constants (B=2, S=2048, D=1024, H=16, hd=64)
#define DIMD 1024
#define SEQ  2048
#define NH   16
#define MROWS 4096   // B*S

typedef __bf16 bf16_t;
typedef bf16_t bf16x8 __attribute__((ext_vector_type(8)));
typedef float  f32x4  __attribute__((ext_vector_type(4)));
typedef unsigned short u16;
typedef unsigned short u16x4 __attribute__((ext_vector_type(4)));
typedef unsigned short u16x8 __attribute__((ext_vector_type(8)));
typedef unsigned int   u32;
typedef u32 u32x2 __attribute__((ext_vector_type(2)));

static __device__ __forceinline__ f32x4 mfma16(bf16x8 a, bf16x8 b, f32x4 c) {
    return __builtin_amdgcn_mfma_f32_16x16x32_bf16(a, b, c, 0, 0, 0);
}

static __device__ __forceinline__ float fast_exp2(float x) {
#if __has_builtin(__builtin_amdgcn_exp2f)
    return __builtin_amdgcn_exp2f(x);
#else
    return exp2f(x);
#endif
}

// async global->LDS 16B per lane; lds dest must be wave-uniform base + lane*16
#define GLD16(gsrc, ldst) __builtin_amdgcn_global_load_lds(                    \
    (const __attribute__((address_space(1))) unsigned int*)(gsrc),             \
    (__attribute__((address_space(3))) unsigned int*)(ldst), 16, 0, 0)

// Split fp32 into hi/lo bf16 by truncation: x ~= hi + lo, rel err <= 2^-16
static __device__ __forceinline__ void split_bf16(float x, u16& h, u16& l) {
    u32 u = __float_as_uint(x);
    u16 hu = (u16)(u >> 16);
    float xh = __uint_as_float((u32)hu << 16);
    float lo = x - xh;
    h = hu;
    l = (u16)(__float_as_uint(lo) >> 16);
}

// pack two fp32 -> dword of 2 bf16 (truncate)
static __device__ __forceinline__ u32 pack_bf16(float a, float b) {
    return (__float_as_uint(a) >> 16) | (__float_as_uint(b) & 0xffff0000u);
}

// ---------------------------------------------------------------------------
// Kernel 1: W[1024][1024] f32 -> W^T split hi/lo bf16 in chunk-major tile
// layout for global_load_lds staging:
//   region(nt,kt) = (nt*32+kt)*4096 elems; within: chunk cc (=k8) 0..3,
//   row r (=n%128) 0..127, elem e (=k%8): offset cc*1024 + r*8 + e.
// Grid (kt 32, nt 8, z 3), 256 thr.
// ---------------------------------------------------------------------------
__global__ __launch_bounds__(256) void transWs3(
    const float* __restrict__ w0, const float* __restrict__ w1, const float* __restrict__ w2,
    u16* __restrict__ WTsH, u16* __restrict__ WTsL) {
    const int z = blockIdx.z;
    const float* W = z == 0 ? w0 : z == 1 ? w1 : w2;
    __shared__ u16 Hs[4096], Ls[4096];
    const int tid = threadIdx.x;
    const int kt = blockIdx.x, nt = blockIdx.y;
    const int n0 = nt * 128, k0 = kt * 32;
    // read 32k x 128n f32 coalesced; write transposed+split into LDS
    #pragma unroll
    for (int i = 0; i < 4; i++) {
        int f = i * 256 + tid;
        int kr = f >> 5, nc4 = (f & 31) * 4;
        f32x4 w = *(const f32x4*)&W[(size_t)(k0 + kr) * DIMD + n0 + nc4];
        int cc = kr >> 3, e = kr & 7;
        #pragma unroll
        for (int j = 0; j < 4; j++) {
            u16 hh, ll; split_bf16(w[j], hh, ll);
            Hs[cc * 1024 + (nc4 + j) * 8 + e] = hh;
            Ls[cc * 1024 + (nc4 + j) * 8 + e] = ll;
        }
    }
    __syncthreads();
    const size_t base = (size_t)z * (DIMD * DIMD) + (size_t)(nt * 32 + kt) * 4096;
    #pragma unroll
    for (int i = 0; i < 2; i++) {
        int idx = (i * 256 + tid) * 8;
        *(u16x8*)(WTsH + base + idx) = *(const u16x8*)&Hs[idx];
        *(u16x8*)(WTsL + base + idx) = *(const u16x8*)&Ls[idx];
    }
}

// ---------------------------------------------------------------------------
// Kernel 2: 3 projection GEMMs (z = q/k/v). P = X @ W, split-bf16 (3 MFMA).
//   A: f32 X, split in-kernel, staged chunk-major in LDS.
//   B: pre-split WTs, staged via global_load_lds (async, 16B), chunk-major.
// Chunk-major [cc*128 + r]*8 gives conflict-free (2-way) b128 frag reads
// with NO padding (bank = 4r % 32). Block 256 (4 waves 2x2), tile 128x128,
// BK=32, LDS 32KB -> 3 blocks/CU.
// ---------------------------------------------------------------------------
__global__ __launch_bounds__(256, 3) void proj4(
    const float* __restrict__ xq, const float* __restrict__ xk, const float* __restrict__ xv,
    const u16* __restrict__ WTsH, const u16* __restrict__ WTsL,
    u16* __restrict__ qh, u16* __restrict__ ql,
    u16* __restrict__ kh, u16* __restrict__ kl,
    u16* __restrict__ vh) {

    const int z = blockIdx.z;
    const float* X = z == 0 ? xq : z == 1 ? xk : xv;
    const u16* BH = WTsH + (size_t)z * (DIMD * DIMD);
    const u16* BL = WTsL + (size_t)z * (DIMD * DIMD);
    u16* outH = z == 0 ? qh : z == 1 ? kh : vh;
    u16* outL = z == 0 ? ql : kl;               // unused when z==2 (guarded)
    const float oscale = z == 0 ? 0.0450842200278f : 1.0f;  // (1/32)*log2(e)

    __shared__ u16 lds[16384];                  // AsH | AsL | BsH | BsL (4096 each)
    u16* AsH = lds;
    u16* AsL = lds + 4096;
    u16* BsH = lds + 8192;
    u16* BsL = lds + 12288;

    const int tid  = threadIdx.x;
    const int lane = tid & 63, wave = tid >> 6;
    const int quad = lane >> 4, l16 = lane & 15;
    const int wy = wave >> 1, wx = wave & 1;
    const int m0 = blockIdx.y * 128;
    const int n0 = blockIdx.x * 128;
    const size_t Bregion0 = (size_t)(blockIdx.x * 32) * 4096;

    f32x4 acc[4][4];
    #pragma unroll
    for (int mt = 0; mt < 4; mt++)
        #pragma unroll
        for (int nt = 0; nt < 4; nt++) acc[mt][nt] = (f32x4)0.0f;

    for (int kt = 0; kt < 32; kt++) {
        const int k0 = kt * 32;
        // B: async staging, 4 x global_load_lds dwordx4 per thread
        {
            const size_t rb = Bregion0 + (size_t)kt * 4096;
            int c0 = tid, c1 = 256 + tid;
            GLD16(BH + rb + c0 * 8, &BsH[c0 * 8]);
            GLD16(BH + rb + c1 * 8, &BsH[c1 * 8]);
            GLD16(BL + rb + c0 * 8, &BsL[c0 * 8]);
            GLD16(BL + rb + c1 * 8, &BsL[c1 * 8]);
        }
        // A: f32 -> split hi/lo, chunk-major store
        #pragma unroll
        for (int i = 0; i < 4; i++) {
            int f = i * 256 + tid;
            int r = f >> 3, c4 = (f & 7) * 4;
            f32x4 a = *(const f32x4*)&X[(size_t)(m0 + r) * DIMD + k0 + c4];
            int cc = c4 >> 3, e = c4 & 7;
            u16x4 h4, l4;
            #pragma unroll
            for (int j = 0; j < 4; j++) {
                u16 hh, ll; split_bf16(a[j], hh, ll);
                h4[j] = hh; l4[j] = ll;
            }
            *(u16x4*)&AsH[(cc * 128 + r) * 8 + e] = h4;
            *(u16x4*)&AsL[(cc * 128 + r) * 8 + e] = l4;
        }
        __syncthreads();   // drains vmcnt (async B) + lgkm (A writes)

        bf16x8 aH[4], aL[4], bH[4], bL[4];
        #pragma unroll
        for (int mt = 0; mt < 4; mt++) {
            int r = wy * 64 + mt * 16 + l16;
            aH[mt] = *(const bf16x8*)&AsH[(quad * 128 + r) * 8];
            aL[mt] = *(const bf16x8*)&AsL[(quad * 128 + r) * 8];
        }
        #pragma unroll
        for (int nt = 0; nt < 4; nt++) {
            int r = wx * 64 + nt * 16 + l16;
            bH[nt] = *(const bf16x8*)&BsH[(quad * 128 + r) * 8];
            bL[nt] = *(const bf16x8*)&BsL[(quad * 128 + r) * 8];
        }
        #pragma unroll
        for (int mt = 0; mt < 4; mt++)
            #pragma unroll
            for (int nt = 0; nt < 4; nt++) {
                acc[mt][nt] = mfma16(aH[mt], bH[nt], acc[mt][nt]);
                acc[mt][nt] = mfma16(aH[mt], bL[nt], acc[mt][nt]);
                acc[mt][nt] = mfma16(aL[mt], bH[nt], acc[mt][nt]);
            }
        __syncthreads();
    }

    #pragma unroll
    for (int mt = 0; mt < 4; mt++)
        #pragma unroll
        for (int nt = 0; nt < 4; nt++)
            #pragma unroll
            for (int r = 0; r < 4; r++) {
                int row = m0 + wy * 64 + mt * 16 + quad * 4 + r;
                int col = n0 + wx * 64 + nt * 16 + l16;
                u16 hh, ll; split_bf16(acc[mt][nt][r] * oscale, hh, ll);
                outH[(size_t)row * DIMD + col] = hh;
                if (z != 2) outL[(size_t)row * DIMD + col] = ll;
            }
}

// ---------------------------------------------------------------------------
// Kernel 3: per-head V transpose: vh slab [bh][2048][64] -> vt [bh][64][2048]
// ---------------------------------------------------------------------------
__global__ __launch_bounds__(256) void transposeV(
    const u16* __restrict__ vh, u16* __restrict__ vt) {
    __shared__ u16 Ls[64][72];
    const int tid = threadIdx.x;
    const int bh = blockIdx.y;
    const int s0 = blockIdx.x * 64;
    const size_t slab = (size_t)bh * (SEQ * 64);
    #pragma unroll
    for (int i = 0; i < 2; i++) {
        int f = i * 256 + tid;
        int r = f >> 3, c = (f & 7) * 8;
        *(u16x8*)&Ls[r][c] = *(const u16x8*)(vh + slab + (size_t)(s0 + r) * 64 + c);
    }
    __syncthreads();
    #pragma unroll
    for (int i = 0; i < 2; i++) {
        int f = i * 256 + tid;
        int d = f >> 3, j = (f & 7) * 8;
        u16x8 o;
        #pragma unroll
        for (int jj = 0; jj < 8; jj++) o[jj] = Ls[j + jj][d];
        *(u16x8*)(vt + slab + (size_t)d * SEQ + s0 + j) = o;
    }
}

// ---------------------------------------------------------------------------
// Kernel 4: flash attention, S^T formulation, LDS-staged K/V, double-buffered.
//   Block = 4 waves (256 thr), Q-tile 128 (32 q/wave, mq=2), KV-tile 64/iter,
//   full KV sweep per block (no combine). One __syncthreads per tile.
//   S^T = K·Q^T: softmax state per-lane scalar (2 shuffles per reduction).
//   P round-trip through wave-local LDS (C-layout -> B-operand layout).
// Grid (16,32) = 512 blocks = 2/CU (LDS 72KB), __launch_bounds__(256,2).
// ---------------------------------------------------------------------------
__global__ __launch_bounds__(256, 2) void flash4(
    const u16* __restrict__ qh, const u16* __restrict__ ql,
    const u16* __restrict__ kh, const u16* __restrict__ kl,
    const u16* __restrict__ vt,
    float* __restrict__ out) {

    __shared__ u16 KH[2][64][72], KL[2][64][72], VTs[2][64][72];
    __shared__ u16 Ps[4][32][72];

    const int tid  = threadIdx.x;
    const int lane = tid & 63, wv = tid >> 6;
    const int quad = lane >> 4, l16 = lane & 15;
    const int bh = blockIdx.y, b = bh >> 4, h = bh & 15;
    const size_t slab = (size_t)bh * (SEQ * 64);
    const int q0 = blockIdx.x * 128 + wv * 32;

    // Q fragments (hi/lo), rows q0 + mq*16 + l16
    bf16x8 qfH[2][2], qfL[2][2];
    #pragma unroll
    for (int mq = 0; mq < 2; mq++) {
        const size_t rb = slab + (size_t)(q0 + mq * 16 + l16) * 64;
        #pragma unroll
        for (int kk = 0; kk < 2; kk++) {
            qfH[mq][kk] = *(const bf16x8*)(qh + rb + kk * 32 + quad * 8);
            qfL[mq][kk] = *(const bf16x8*)(ql + rb + kk * 32 + quad * 8);
        }
    }

    f32x4 O[2][4];
    float M[2] = {-3.0e38f, -3.0e38f}, L[2] = {0.0f, 0.0f};
    #pragma unroll
    for (int mq = 0; mq < 2; mq++)
        #pragma unroll
        for (int nv = 0; nv < 4; nv++) O[mq][nv] = (f32x4)0.0f;

    // staging: 6 x 16B chunks per thread (KH 2, KL 2, VT 2)
    const int f0 = tid, f1 = 256 + tid;
    const int r0 = f0 >> 3, c0 = (f0 & 7) * 8;
    const int r1 = f1 >> 3, c1 = (f1 & 7) * 8;
    u16x8 s0, s1, s2, s3, s4, s5;

    // preload tile 0
    {
        const int j0 = 0;
        s0 = *(const u16x8*)(kh + slab + (size_t)(j0 + r0) * 64 + c0);
        s1 = *(const u16x8*)(kh + slab + (size_t)(j0 + r1) * 64 + c1);
        s2 = *(const u16x8*)(kl + slab + (size_t)(j0 + r0) * 64 + c0);
        s3 = *(const u16x8*)(kl + slab + (size_t)(j0 + r1) * 64 + c1);
        s4 = *(const u16x8*)(vt + slab + (size_t)r0 * SEQ + j0 + c0);
        s5 = *(const u16x8*)(vt + slab + (size_t)r1 * SEQ + j0 + c1);
    }
    *(u16x8*)&KH[0][r0][c0] = s0;  *(u16x8*)&KH[0][r1][c1] = s1;
    *(u16x8*)&KL[0][r0][c0] = s2;  *(u16x8*)&KL[0][r1][c1] = s3;
    *(u16x8*)&VTs[0][r0][c0] = s4; *(u16x8*)&VTs[0][r1][c1] = s5;
    __syncthreads();

    for (int t = 0; t < 32; t++) {
        const int cur = t & 1;
        if (t < 31) {   // prefetch next tile into registers (overlaps compute)
            const int j0 = (t + 1) * 64;
            s0 = *(const u16x8*)(kh + slab + (size_t)(j0 + r0) * 64 + c0);
            s1 = *(const u16x8*)(kh + slab + (size_t)(j0 + r1) * 64 + c1);
            s2 = *(const u16x8*)(kl + slab + (size_t)(j0 + r0) * 64 + c0);
            s3 = *(const u16x8*)(kl + slab + (size_t)(j0 + r1) * 64 + c1);
            s4 = *(const u16x8*)(vt + slab + (size_t)r0 * SEQ + j0 + c0);
            s5 = *(const u16x8*)(vt + slab + (size_t)r1 * SEQ + j0 + c1);
        }

        // S^T = K·Q^T (split: Kh·Qh + Kl·Qh + Kh·Ql)
        f32x4 St[2][4];
        #pragma unroll
        for (int mq = 0; mq < 2; mq++)
            #pragma unroll
            for (int nt = 0; nt < 4; nt++) St[mq][nt] = (f32x4)0.0f;
        #pragma unroll
        for (int nt = 0; nt < 4; nt++) {
            const int rB = nt * 16 + l16;
            #pragma unroll
            for (int kk = 0; kk < 2; kk++) {
                bf16x8 kHf = *(const bf16x8*)&KH[cur][rB][kk * 32 + quad * 8];
                bf16x8 kLf = *(const bf16x8*)&KL[cur][rB][kk * 32 + quad * 8];
                #pragma unroll
                for (int mq = 0; mq < 2; mq++) {
                    St[mq][nt] = mfma16(kHf, qfH[mq][kk], St[mq][nt]);
                    St[mq][nt] = mfma16(kLf, qfH[mq][kk], St[mq][nt]);
                    St[mq][nt] = mfma16(kHf, qfL[mq][kk], St[mq][nt]);
                }
            }
        }

        // online softmax: per-lane scalar state (lane col = one q)
        #pragma unroll
        for (int mq = 0; mq < 2; mq++) {
            float mx = St[mq][0][0];
            #pragma unroll
            for (int nt = 0; nt < 4; nt++)
                #pragma unroll
                for (int r = 0; r < 4; r++) mx = fmaxf(mx, St[mq][nt][r]);
            mx = fmaxf(mx, __shfl_xor(mx, 16));
            mx = fmaxf(mx, __shfl_xor(mx, 32));
            float Mn = fmaxf(M[mq], mx);
            float al = fast_exp2(M[mq] - Mn);
            M[mq] = Mn;
            float rs = 0.0f;
            #pragma unroll
            for (int nt = 0; nt < 4; nt++)
                #pragma unroll
                for (int r = 0; r < 4; r++) {
                    float p = fast_exp2(St[mq][nt][r] - Mn);
                    St[mq][nt][r] = p;
                    rs += p;
                }
            rs += __shfl_xor(rs, 16);
            rs += __shfl_xor(rs, 32);
            L[mq] = L[mq] * al + rs;
            #pragma unroll
            for (int nv = 0; nv < 4; nv++) O[mq][nv] *= al;
            #pragma unroll
            for (int nt = 0; nt < 4; nt++) {
                u32x2 d;
                d[0] = pack_bf16(St[mq][nt][0], St[mq][nt][1]);
                d[1] = pack_bf16(St[mq][nt][2], St[mq][nt][3]);
                *(u32x2*)&Ps[wv][mq * 16 + l16][nt * 16 + quad * 4] = d;
            }
        }

        // O^T += V^T · P^T   (wave-local P, ordering via lgkmcnt)
        #pragma unroll
        for (int kk = 0; kk < 2; kk++) {
            bf16x8 pB[2];
            #pragma unroll
            for (int mq = 0; mq < 2; mq++)
                pB[mq] = *(const bf16x8*)&Ps[wv][mq * 16 + l16][kk * 32 + quad * 8];
            #pragma unroll
            for (int nv = 0; nv < 4; nv++) {
                bf16x8 vF = *(const bf16x8*)&VTs[cur][nv * 16 + l16][kk * 32 + quad * 8];
                #pragma unroll
                for (int mq = 0; mq < 2; mq++)
                    O[mq][nv] = mfma16(vF, pB[mq], O[mq][nv]);
            }
        }

        if (t < 31) {   // write prefetched tile into the other buffer
            const int nb = cur ^ 1;
            *(u16x8*)&KH[nb][r0][c0] = s0;  *(u16x8*)&KH[nb][r1][c1] = s1;
            *(u16x8*)&KL[nb][r0][c0] = s2;  *(u16x8*)&KL[nb][r1][c1] = s3;
            *(u16x8*)&VTs[nb][r0][c0] = s4; *(u16x8*)&VTs[nb][r1][c1] = s5;
        }
        __syncthreads();
    }

    // epilogue: out[b, q, h*64 + d] = O / L  (f32x4 per lane)
    #pragma unroll
    for (int mq = 0; mq < 2; mq++) {
        float inv = 1.0f / L[mq];
        int row = q0 + mq * 16 + l16;
        size_t obase = ((size_t)(b * SEQ + row)) * DIMD + h * 64;
        #pragma unroll
        for (int nv = 0; nv < 4; nv++) {
            f32x4 o = O[mq][nv] * inv;
            *(f32x4*)&out[obase + nv * 16 + quad * 4] = o;
        }
    }
}

// ---------------------------------------------------------------------------
extern "C" void kernel_launch(void* const* d_in, const int* in_sizes, int n_in,
                              void* d_out, int out_size, void* d_ws, size_t ws_size,
                              hipStream_t stream) {
    const float* q  = (const float*)d_in[0];
    const float* k  = (const float*)d_in[1];
    const float* v  = (const float*)d_in[2];
    const float* wq = (const float*)d_in[3];
    const float* wk = (const float*)d_in[4];
    const float* wv = (const float*)d_in[5];
    float* out = (float*)d_out;

    char* ws = (char*)d_ws;
    const size_t MB = 1 << 20;
    // WTs (12MB) dead after proj4; vt overlays it.
    u16* WTsH = (u16*)(ws + 0);
    u16* WTsL = (u16*)(ws + 6 * MB);
    u16* vt   = (u16*)(ws + 0);          // overlays WTs (dead by transposeV)
    u16* qh = (u16*)(ws + 12 * MB);
    u16* ql = (u16*)(ws + 20 * MB);
    u16* kh = (u16*)(ws + 28 * MB);
    u16* kl = (u16*)(ws + 36 * MB);
    u16* vh = (u16*)(ws + 44 * MB);      // total 52 MB

    transWs3<<<dim3(32, 8, 3), 256, 0, stream>>>(wq, wk, wv, WTsH, WTsL);

    proj4<<<dim3(8, 32, 3), 256, 0, stream>>>(
        q, k, v, WTsH, WTsL, qh, ql, kh, kl, vh);

    transposeV<<<dim3(SEQ / 64, 2 * NH), 256, 0, stream>>>(vh, vt);

    flash4<<<dim3(SEQ / 128, 2 * NH), 256, 0, stream>>>(
        qh, ql, kh, kl, vt, out);
}

// Round 6
// 267.338 us; speedup vs baseline: 1.4931x; 1.0080x over previous
//
#include <hip/hip_runtime.h>
#include <hip/hip_bf16.h>
#include <stdint.h>

// Problem constants (B=2, S=2048, D=1024, H=16, hd=64)
#define DIMD 1024
#define SEQ  2048
#define NH   16
#define MROWS 4096   // B*S
#define NQ   65536   // total q rows across (b,h)

typedef __bf16 bf16_t;
typedef bf16_t bf16x8 __attribute__((ext_vector_type(8)));
typedef float  f32x4  __attribute__((ext_vector_type(4)));
typedef unsigned short u16;
typedef unsigned short u16x4 __attribute__((ext_vector_type(4)));
typedef unsigned short u16x8 __attribute__((ext_vector_type(8)));
typedef unsigned int   u32;
typedef u32 u32x2 __attribute__((ext_vector_type(2)));

static __device__ __forceinline__ f32x4 mfma16(bf16x8 a, bf16x8 b, f32x4 c) {
    return __builtin_amdgcn_mfma_f32_16x16x32_bf16(a, b, c, 0, 0, 0);
}

static __device__ __forceinline__ float fast_exp2(float x) {
#if __has_builtin(__builtin_amdgcn_exp2f)
    return __builtin_amdgcn_exp2f(x);
#else
    return exp2f(x);
#endif
}

// async global->LDS 16B per lane; lds dest must be wave-uniform base + lane*16
#define GLD16(gsrc, ldst) __builtin_amdgcn_global_load_lds(                    \
    (const __attribute__((address_space(1))) unsigned int*)(gsrc),             \
    (__attribute__((address_space(3))) unsigned int*)(ldst), 16, 0, 0)

// Split fp32 into hi/lo bf16 by truncation: x ~= hi + lo, rel err <= 2^-16
static __device__ __forceinline__ void split_bf16(float x, u16& h, u16& l) {
    u32 u = __float_as_uint(x);
    u16 hu = (u16)(u >> 16);
    float xh = __uint_as_float((u32)hu << 16);
    float lo = x - xh;
    h = hu;
    l = (u16)(__float_as_uint(lo) >> 16);
}

static __device__ __forceinline__ u32 pack_bf16(float a, float b) {
    return (__float_as_uint(a) >> 16) | (__float_as_uint(b) & 0xffff0000u);
}
static __device__ __forceinline__ u32 pack_bf16_rn(float a, float b) {
    u32 ua = __float_as_uint(a) + 0x8000u;
    u32 ub = __float_as_uint(b) + 0x8000u;
    return (ua >> 16) | (ub & 0xffff0000u);
}
static __device__ __forceinline__ float bf_to_f(u16 v) {
    return __uint_as_float((u32)v << 16);
}

// ---------------------------------------------------------------------------
// Kernel 1: W[1024][1024] f32 -> W^T split hi/lo bf16, chunk-major tile layout
// for global_load_lds: region(nt,kt)=(nt*32+kt)*4096; within: cc*1024+r*8+e.
// Grid (kt 32, nt 8, z 3), 256 thr.
// ---------------------------------------------------------------------------
__global__ __launch_bounds__(256) void transWs3(
    const float* __restrict__ w0, const float* __restrict__ w1, const float* __restrict__ w2,
    u16* __restrict__ WTsH, u16* __restrict__ WTsL) {
    const int z = blockIdx.z;
    const float* W = z == 0 ? w0 : z == 1 ? w1 : w2;
    __shared__ u16 Hs[4096], Ls[4096];
    const int tid = threadIdx.x;
    const int kt = blockIdx.x, nt = blockIdx.y;
    const int n0 = nt * 128, k0 = kt * 32;
    #pragma unroll
    for (int i = 0; i < 4; i++) {
        int f = i * 256 + tid;
        int kr = f >> 5, nc4 = (f & 31) * 4;
        f32x4 w = *(const f32x4*)&W[(size_t)(k0 + kr) * DIMD + n0 + nc4];
        int cc = kr >> 3, e = kr & 7;
        #pragma unroll
        for (int j = 0; j < 4; j++) {
            u16 hh, ll; split_bf16(w[j], hh, ll);
            Hs[cc * 1024 + (nc4 + j) * 8 + e] = hh;
            Ls[cc * 1024 + (nc4 + j) * 8 + e] = ll;
        }
    }
    __syncthreads();
    const size_t base = (size_t)z * (DIMD * DIMD) + (size_t)(nt * 32 + kt) * 4096;
    #pragma unroll
    for (int i = 0; i < 2; i++) {
        int idx = (i * 256 + tid) * 8;
        *(u16x8*)(WTsH + base + idx) = *(const u16x8*)&Hs[idx];
        *(u16x8*)(WTsL + base + idx) = *(const u16x8*)&Ls[idx];
    }
}

// ---------------------------------------------------------------------------
// Kernel 2: 3 projection GEMMs (z = q/k/v). P = X @ W, split-bf16 (3 MFMA).
// Grid (x = m-tile 32, y = n-tile 8, z = 3): blocks sharing an A-tile are
// 32 apart in block id -> same XCD (id%8) -> A-tile hits that XCD's L2.
// Outputs plain [4096][1024] row-major (layout-agnostic w.r.t. the head
// reshape). z==2 (V) writes hi-only vh; z<2 write hi/lo.
// ---------------------------------------------------------------------------
__global__ __launch_bounds__(256, 3) void proj6(
    const float* __restrict__ xq, const float* __restrict__ xk, const float* __restrict__ xv,
    const u16* __restrict__ WTsH, const u16* __restrict__ WTsL,
    u16* __restrict__ qh, u16* __restrict__ ql,
    u16* __restrict__ kh, u16* __restrict__ kl,
    u16* __restrict__ vh) {

    const int z = blockIdx.z;
    const float* X = z == 0 ? xq : z == 1 ? xk : xv;
    const u16* BH = WTsH + (size_t)z * (DIMD * DIMD);
    const u16* BL = WTsL + (size_t)z * (DIMD * DIMD);
    u16* outH = z == 0 ? qh : z == 1 ? kh : vh;
    u16* outL = z == 0 ? ql : kl;               // unused when z==2 (guarded)
    const float oscale = z == 0 ? 0.0450842200278f : 1.0f;  // (1/32)*log2(e)

    __shared__ u16 lds[16384];                  // AsH | AsL | BsH | BsL
    u16* AsH = lds;
    u16* AsL = lds + 4096;
    u16* BsH = lds + 8192;
    u16* BsL = lds + 12288;

    const int tid  = threadIdx.x;
    const int lane = tid & 63, wave = tid >> 6;
    const int quad = lane >> 4, l16 = lane & 15;
    const int wy = wave >> 1, wx = wave & 1;
    const int m0 = blockIdx.x * 128;            // row tile (A)
    const int n0 = blockIdx.y * 128;            // col tile (B)
    const size_t Bregion0 = (size_t)(blockIdx.y * 32) * 4096;

    f32x4 acc[4][4];
    #pragma unroll
    for (int mt = 0; mt < 4; mt++)
        #pragma unroll
        for (int nt = 0; nt < 4; nt++) acc[mt][nt] = (f32x4)0.0f;

    for (int kt = 0; kt < 32; kt++) {
        const int k0 = kt * 32;
        {   // B: async staging (4 x dwordx4/thread)
            const size_t rb = Bregion0 + (size_t)kt * 4096;
            int c0 = tid, c1 = 256 + tid;
            GLD16(BH + rb + c0 * 8, &BsH[c0 * 8]);
            GLD16(BH + rb + c1 * 8, &BsH[c1 * 8]);
            GLD16(BL + rb + c0 * 8, &BsL[c0 * 8]);
            GLD16(BL + rb + c1 * 8, &BsL[c1 * 8]);
        }
        // A: f32 -> split hi/lo, chunk-major store
        #pragma unroll
        for (int i = 0; i < 4; i++) {
            int f = i * 256 + tid;
            int r = f >> 3, c4 = (f & 7) * 4;
            f32x4 a = *(const f32x4*)&X[(size_t)(m0 + r) * DIMD + k0 + c4];
            int cc = c4 >> 3, e = c4 & 7;
            u16x4 h4, l4;
            #pragma unroll
            for (int j = 0; j < 4; j++) {
                u16 hh, ll; split_bf16(a[j], hh, ll);
                h4[j] = hh; l4[j] = ll;
            }
            *(u16x4*)&AsH[(cc * 128 + r) * 8 + e] = h4;
            *(u16x4*)&AsL[(cc * 128 + r) * 8 + e] = l4;
        }
        __syncthreads();

        bf16x8 aH[4], aL[4], bH[4], bL[4];
        #pragma unroll
        for (int mt = 0; mt < 4; mt++) {
            int r = wy * 64 + mt * 16 + l16;
            aH[mt] = *(const bf16x8*)&AsH[(quad * 128 + r) * 8];
            aL[mt] = *(const bf16x8*)&AsL[(quad * 128 + r) * 8];
        }
        #pragma unroll
        for (int nt = 0; nt < 4; nt++) {
            int r = wx * 64 + nt * 16 + l16;
            bH[nt] = *(const bf16x8*)&BsH[(quad * 128 + r) * 8];
            bL[nt] = *(const bf16x8*)&BsL[(quad * 128 + r) * 8];
        }
        #pragma unroll
        for (int mt = 0; mt < 4; mt++)
            #pragma unroll
            for (int nt = 0; nt < 4; nt++) {
                acc[mt][nt] = mfma16(aH[mt], bH[nt], acc[mt][nt]);
                acc[mt][nt] = mfma16(aH[mt], bL[nt], acc[mt][nt]);
                acc[mt][nt] = mfma16(aL[mt], bH[nt], acc[mt][nt]);
            }
        __syncthreads();
    }

    #pragma unroll
    for (int mt = 0; mt < 4; mt++)
        #pragma unroll
        for (int nt = 0; nt < 4; nt++)
            #pragma unroll
            for (int r = 0; r < 4; r++) {
                int row = m0 + wy * 64 + mt * 16 + quad * 4 + r;
                int col = n0 + wx * 64 + nt * 16 + l16;
                u16 hh, ll; split_bf16(acc[mt][nt][r] * oscale, hh, ll);
                outH[(size_t)row * DIMD + col] = hh;
                if (z != 2) outL[(size_t)row * DIMD + col] = ll;
            }
}

// ---------------------------------------------------------------------------
// Kernel 3: per-head V transpose. vh is the flat projection [4096][1024];
// head slab bh = contiguous 128 rows reinterpreted as [2048 sq][64 d]
// (direct-reshape semantics). Output vt[bh][64 d][2048 sq].
// ---------------------------------------------------------------------------
__global__ __launch_bounds__(256) void transposeV(
    const u16* __restrict__ vh, u16* __restrict__ vt) {
    __shared__ u16 Ls[64][72];
    const int tid = threadIdx.x;
    const int bh = blockIdx.y;
    const int s0 = blockIdx.x * 64;
    const size_t slab = (size_t)bh * (SEQ * 64);
    #pragma unroll
    for (int i = 0; i < 2; i++) {
        int f = i * 256 + tid;
        int r = f >> 3, c = (f & 7) * 8;
        *(u16x8*)&Ls[r][c] = *(const u16x8*)(vh + slab + (size_t)(s0 + r) * 64 + c);
    }
    __syncthreads();
    #pragma unroll
    for (int i = 0; i < 2; i++) {
        int f = i * 256 + tid;
        int d = f >> 3, j = (f & 7) * 8;
        u16x8 o;
        #pragma unroll
        for (int jj = 0; jj < 8; jj++) o[jj] = Ls[j + jj][d];
        *(u16x8*)(vt + slab + (size_t)d * SEQ + s0 + j) = o;
    }
}

// ---------------------------------------------------------------------------
// Kernel 4: flash attention, S^T formulation, KV-split 2, single-buffered
// K/V LDS with register prefetch. Block 4 waves, Q-tile 128 (mq=2/wave).
// Grid (bh 32, qtile 16, z 2); 1024 blocks, LDS 45KB -> 3 blocks/CU.
// Writes bf16 unnormalized O partials + M,L per half; combine merges.
// ---------------------------------------------------------------------------
__global__ __launch_bounds__(256, 3) void flash6(
    const u16* __restrict__ qh, const u16* __restrict__ ql,
    const u16* __restrict__ kh, const u16* __restrict__ kl,
    const u16* __restrict__ vt,
    u16* __restrict__ Opart, float* __restrict__ Mpart, float* __restrict__ Lpart) {

    __shared__ u16 KH[64][72], KL[64][72], VTs[64][72];
    __shared__ u16 Ps[4][32][72];

    const int tid  = threadIdx.x;
    const int lane = tid & 63, wv = tid >> 6;
    const int quad = lane >> 4, l16 = lane & 15;
    const int bh = blockIdx.x, z = blockIdx.z;
    const size_t slab = (size_t)bh * (SEQ * 64);
    const int q0 = blockIdx.y * 128 + wv * 32;
    const int jbase = z * 1024;

    bf16x8 qfH[2][2], qfL[2][2];
    #pragma unroll
    for (int mq = 0; mq < 2; mq++) {
        const size_t rb = slab + (size_t)(q0 + mq * 16 + l16) * 64;
        #pragma unroll
        for (int kk = 0; kk < 2; kk++) {
            qfH[mq][kk] = *(const bf16x8*)(qh + rb + kk * 32 + quad * 8);
            qfL[mq][kk] = *(const bf16x8*)(ql + rb + kk * 32 + quad * 8);
        }
    }

    f32x4 O[2][4];
    float M[2] = {-3.0e38f, -3.0e38f}, L[2] = {0.0f, 0.0f};
    #pragma unroll
    for (int mq = 0; mq < 2; mq++)
        #pragma unroll
        for (int nv = 0; nv < 4; nv++) O[mq][nv] = (f32x4)0.0f;

    const int f0 = tid, f1 = 256 + tid;
    const int r0 = f0 >> 3, c0 = (f0 & 7) * 8;
    const int r1 = f1 >> 3, c1 = (f1 & 7) * 8;
    u16x8 s0, s1, s2, s3, s4, s5;

    {   // preload tile 0
        const int j0 = jbase;
        s0 = *(const u16x8*)(kh + slab + (size_t)(j0 + r0) * 64 + c0);
        s1 = *(const u16x8*)(kh + slab + (size_t)(j0 + r1) * 64 + c1);
        s2 = *(const u16x8*)(kl + slab + (size_t)(j0 + r0) * 64 + c0);
        s3 = *(const u16x8*)(kl + slab + (size_t)(j0 + r1) * 64 + c1);
        s4 = *(const u16x8*)(vt + slab + (size_t)r0 * SEQ + j0 + c0);
        s5 = *(const u16x8*)(vt + slab + (size_t)r1 * SEQ + j0 + c1);
    }
    *(u16x8*)&KH[r0][c0] = s0;  *(u16x8*)&KH[r1][c1] = s1;
    *(u16x8*)&KL[r0][c0] = s2;  *(u16x8*)&KL[r1][c1] = s3;
    *(u16x8*)&VTs[r0][c0] = s4; *(u16x8*)&VTs[r1][c1] = s5;
    __syncthreads();

    for (int t = 0; t < 16; t++) {
        if (t < 15) {   // prefetch next tile into registers
            const int j0 = jbase + (t + 1) * 64;
            s0 = *(const u16x8*)(kh + slab + (size_t)(j0 + r0) * 64 + c0);
            s1 = *(const u16x8*)(kh + slab + (size_t)(j0 + r1) * 64 + c1);
            s2 = *(const u16x8*)(kl + slab + (size_t)(j0 + r0) * 64 + c0);
            s3 = *(const u16x8*)(kl + slab + (size_t)(j0 + r1) * 64 + c1);
            s4 = *(const u16x8*)(vt + slab + (size_t)r0 * SEQ + j0 + c0);
            s5 = *(const u16x8*)(vt + slab + (size_t)r1 * SEQ + j0 + c1);
        }

        // S^T = K·Q^T (split: Kh·Qh + Kl·Qh + Kh·Ql)
        f32x4 St[2][4];
        #pragma unroll
        for (int mq = 0; mq < 2; mq++)
            #pragma unroll
            for (int nt = 0; nt < 4; nt++) St[mq][nt] = (f32x4)0.0f;
        #pragma unroll
        for (int nt = 0; nt < 4; nt++) {
            const int rB = nt * 16 + l16;
            #pragma unroll
            for (int kk = 0; kk < 2; kk++) {
                bf16x8 kHf = *(const bf16x8*)&KH[rB][kk * 32 + quad * 8];
                bf16x8 kLf = *(const bf16x8*)&KL[rB][kk * 32 + quad * 8];
                #pragma unroll
                for (int mq = 0; mq < 2; mq++) {
                    St[mq][nt] = mfma16(kHf, qfH[mq][kk], St[mq][nt]);
                    St[mq][nt] = mfma16(kLf, qfH[mq][kk], St[mq][nt]);
                    St[mq][nt] = mfma16(kHf, qfL[mq][kk], St[mq][nt]);
                }
            }
        }

        // online softmax: per-lane scalar state; wave-uniform rescale skip
        #pragma unroll
        for (int mq = 0; mq < 2; mq++) {
            float mx = St[mq][0][0];
            #pragma unroll
            for (int nt = 0; nt < 4; nt++)
                #pragma unroll
                for (int r = 0; r < 4; r++) mx = fmaxf(mx, St[mq][nt][r]);
            mx = fmaxf(mx, __shfl_xor(mx, 16));
            mx = fmaxf(mx, __shfl_xor(mx, 32));
            float Mn = M[mq];
            if (__any(mx > Mn)) {
                Mn = fmaxf(Mn, mx);
                float al = fast_exp2(M[mq] - Mn);
                M[mq] = Mn;
                L[mq] *= al;
                #pragma unroll
                for (int nv = 0; nv < 4; nv++) O[mq][nv] *= al;
            }
            float rs = 0.0f;
            #pragma unroll
            for (int nt = 0; nt < 4; nt++)
                #pragma unroll
                for (int r = 0; r < 4; r++) {
                    float p = fast_exp2(St[mq][nt][r] - Mn);
                    St[mq][nt][r] = p;
                    rs += p;
                }
            rs += __shfl_xor(rs, 16);
            rs += __shfl_xor(rs, 32);
            L[mq] += rs;
            #pragma unroll
            for (int nt = 0; nt < 4; nt++) {
                u32x2 d;
                d[0] = pack_bf16(St[mq][nt][0], St[mq][nt][1]);
                d[1] = pack_bf16(St[mq][nt][2], St[mq][nt][3]);
                *(u32x2*)&Ps[wv][mq * 16 + l16][nt * 16 + quad * 4] = d;
            }
        }

        // O^T += V^T · P^T (wave-local P; intra-wave ordering via lgkmcnt)
        #pragma unroll
        for (int kk = 0; kk < 2; kk++) {
            bf16x8 pB[2];
            #pragma unroll
            for (int mq = 0; mq < 2; mq++)
                pB[mq] = *(const bf16x8*)&Ps[wv][mq * 16 + l16][kk * 32 + quad * 8];
            #pragma unroll
            for (int nv = 0; nv < 4; nv++) {
                bf16x8 vF = *(const bf16x8*)&VTs[nv * 16 + l16][kk * 32 + quad * 8];
                #pragma unroll
                for (int mq = 0; mq < 2; mq++)
                    O[mq][nv] = mfma16(vF, pB[mq], O[mq][nv]);
            }
        }

        __syncthreads();                 // all waves done reading tile t
        if (t < 15) {
            *(u16x8*)&KH[r0][c0] = s0;  *(u16x8*)&KH[r1][c1] = s1;
            *(u16x8*)&KL[r0][c0] = s2;  *(u16x8*)&KL[r1][c1] = s3;
            *(u16x8*)&VTs[r0][c0] = s4; *(u16x8*)&VTs[r1][c1] = s5;
        }
        __syncthreads();                 // tile t+1 visible
    }

    // epilogue: bf16 unnormalized O + M, L for this half
    const int qgb = bh * SEQ + q0;
    #pragma unroll
    for (int mq = 0; mq < 2; mq++) {
        const int qg = qgb + mq * 16 + l16;
        #pragma unroll
        for (int nv = 0; nv < 4; nv++) {
            u32x2 d;
            d[0] = pack_bf16_rn(O[mq][nv][0], O[mq][nv][1]);
            d[1] = pack_bf16_rn(O[mq][nv][2], O[mq][nv][3]);
            *(u32x2*)(Opart + ((size_t)(z * NQ + qg)) * 64 + nv * 16 + quad * 4) = d;
        }
        if (quad == 0) {
            Mpart[z * NQ + qg] = M[mq];
            Lpart[z * NQ + qg] = L[mq];
        }
    }
}

// ---------------------------------------------------------------------------
// Kernel 5: combine the 2 KV-split halves -> final out [B,S,D]
// ---------------------------------------------------------------------------
__global__ __launch_bounds__(256) void combineK(
    const u16* __restrict__ Opart, const float* __restrict__ Mpart,
    const float* __restrict__ Lpart, float* __restrict__ out) {
    int idx = blockIdx.x * 256 + threadIdx.x;       // NQ*16 threads
    int qg = idx >> 4, c4 = (idx & 15) * 4;
    float M0 = Mpart[qg], M1 = Mpart[NQ + qg];
    float L0 = Lpart[qg], L1 = Lpart[NQ + qg];
    float Ms = fmaxf(M0, M1);
    float w0 = fast_exp2(M0 - Ms), w1 = fast_exp2(M1 - Ms);
    float inv = 1.0f / (w0 * L0 + w1 * L1);
    u16x4 a = *(const u16x4*)&Opart[(size_t)qg * 64 + c4];
    u16x4 b = *(const u16x4*)&Opart[((size_t)NQ + qg) * 64 + c4];
    f32x4 o;
    #pragma unroll
    for (int j = 0; j < 4; j++)
        o[j] = (w0 * bf_to_f(a[j]) + w1 * bf_to_f(b[j])) * inv;
    int bh = qg >> 11, s = qg & 2047;
    int bb = bh >> 4, h = bh & 15;
    *(f32x4*)&out[((size_t)(bb * SEQ + s)) * DIMD + h * 64 + c4] = o;
}

// ---------------------------------------------------------------------------
extern "C" void kernel_launch(void* const* d_in, const int* in_sizes, int n_in,
                              void* d_out, int out_size, void* d_ws, size_t ws_size,
                              hipStream_t stream) {
    const float* q  = (const float*)d_in[0];
    const float* k  = (const float*)d_in[1];
    const float* v  = (const float*)d_in[2];
    const float* wq = (const float*)d_in[3];
    const float* wk = (const float*)d_in[4];
    const float* wv = (const float*)d_in[5];
    float* out = (float*)d_out;

    char* ws = (char*)d_ws;
    const size_t MB = 1 << 20;
    u16* qh   = (u16*)(ws + 0 * MB);        // 8MB
    u16* ql   = (u16*)(ws + 8 * MB);        // 8MB
    u16* kh   = (u16*)(ws + 16 * MB);       // 8MB
    u16* kl   = (u16*)(ws + 24 * MB);       // 8MB
    u16* vh   = (u16*)(ws + 32 * MB);       // 8MB
    u16* vt   = (u16*)(ws + 40 * MB);       // 8MB
    u16* WTsH = (u16*)(ws + 48 * MB);       // 6MB (dead after proj6)
    u16* WTsL = (u16*)(ws + 54 * MB);       // 6MB (dead after proj6)
    u16*   Opart = (u16*)(ws + 48 * MB);    // 16MB, overlays WTs
    float* Mpart = (float*)(ws + 64 * MB);  // 512KB
    float* Lpart = (float*)(ws + 64 * MB + 512 * 1024);  // peak 65MB

    transWs3<<<dim3(32, 8, 3), 256, 0, stream>>>(wq, wk, wv, WTsH, WTsL);

    proj6<<<dim3(32, 8, 3), 256, 0, stream>>>(
        q, k, v, WTsH, WTsL, qh, ql, kh, kl, vh);

    transposeV<<<dim3(SEQ / 64, 2 * NH), 256, 0, stream>>>(vh, vt);

    flash6<<<dim3(2 * NH, SEQ / 128, 2), 256, 0, stream>>>(
        qh, ql, kh, kl, vt, Opart, Mpart, Lpart);

    combineK<<<dim3(NQ * 16 / 256), 256, 0, stream>>>(Opart, Mpart, Lpart, out);
}